// Round 1
// baseline (4602.842 us; speedup 1.0000x reference)
//
#include <hip/hip_runtime.h>
#include <cstdint>
#include <cstddef>

// ---------------------------------------------------------------------------
// AdaAttN fused kernel set, fp16 MFMA path.
//   B=4, C=KP=512, N=M=4096.
//   ws layout (fp16): Fb[4][4096][512] | Gb[4][4096][512] | VT[4][1536][4096]
//     VT rows per batch: [0..511]   = Hs (v-hat, fp16)
//                        [512..1023]= fp16(v-hat^2)   (hi)
//                        [1024..1535]= v-hat^2 - hi    (lo)  -- protects e2-mean^2
// ---------------------------------------------------------------------------

typedef _Float16 f16;
typedef _Float16 f16x8 __attribute__((ext_vector_type(8)));
typedef float f32x4 __attribute__((ext_vector_type(4)));

#define LOG2E 1.44269504088896340736f

__device__ __forceinline__ void async_load16(const void* g, void* l) {
  // global -> LDS direct DMA, 16B per lane; LDS dest = uniform base + lane*16
  __builtin_amdgcn_global_load_lds((const __attribute__((address_space(1))) void*)g,
                                   (__attribute__((address_space(3))) void*)l,
                                   16, 0, 0);
}

// ---------------------------------------------------------------------------
// conv_ik: out[b][i][k] = bias[k] + sum_c wm[k][c] * in[b][c][i]   (fp16 out)
// Used for F (c_1x,f_w) and G (s_1x,g_w).  Tile 64i x 64k, K-chunks of 32.
// A (in, transposed) staged via LDS; B (wm rows) read direct 16B + cvt.
// ---------------------------------------------------------------------------
__global__ __launch_bounds__(256, 2) void conv_ik(
    const float* __restrict__ in, const float* __restrict__ wm,
    const float* __restrict__ bias, f16* __restrict__ out) {
  const int i0 = blockIdx.x * 64;
  const int k0 = blockIdx.y * 64;
  const int b = blockIdx.z;
  const int tid = threadIdx.x;
  const int lane = tid & 63;
  const int wv = tid >> 6;
  const int l15 = lane & 15;
  const int quad = lane >> 4;

  __shared__ __align__(16) f16 a_lds[64 * 40];  // [i][c] stride 40 (pad)

  const float* inb = in + (size_t)b * (512 * 4096);

  f32x4 acc[4];
#pragma unroll
  for (int t = 0; t < 4; ++t) acc[t] = f32x4{0.f, 0.f, 0.f, 0.f};

  for (int cs = 0; cs < 512; cs += 32) {
    __syncthreads();
    // stage in[cs..cs+31][i0..i0+63] -> a_lds[i][c]  (2048 floats)
#pragma unroll
    for (int rep = 0; rep < 2; ++rep) {
      int chunk = tid + rep * 256;  // 0..511
      int cc = chunk >> 4;          // 0..31
      int f4 = chunk & 15;          // 0..15
      float4 v = *(const float4*)(inb + (size_t)(cs + cc) * 4096 + i0 + f4 * 4);
      int ib = f4 * 4;
      a_lds[(ib + 0) * 40 + cc] = (f16)v.x;
      a_lds[(ib + 1) * 40 + cc] = (f16)v.y;
      a_lds[(ib + 2) * 40 + cc] = (f16)v.z;
      a_lds[(ib + 3) * 40 + cc] = (f16)v.w;
    }
    __syncthreads();
    f16x8 af = *(const f16x8*)&a_lds[(wv * 16 + l15) * 40 + quad * 8];
#pragma unroll
    for (int ct = 0; ct < 4; ++ct) {
      const float* wp = wm + (size_t)(k0 + ct * 16 + l15) * 512 + cs + quad * 8;
      float4 w0 = *(const float4*)wp;
      float4 w1 = *(const float4*)(wp + 4);
      f16x8 bf;
      bf[0] = (f16)w0.x; bf[1] = (f16)w0.y; bf[2] = (f16)w0.z; bf[3] = (f16)w0.w;
      bf[4] = (f16)w1.x; bf[5] = (f16)w1.y; bf[6] = (f16)w1.z; bf[7] = (f16)w1.w;
      acc[ct] = __builtin_amdgcn_mfma_f32_16x16x32_f16(af, bf, acc[ct], 0, 0, 0);
    }
  }
#pragma unroll
  for (int ct = 0; ct < 4; ++ct) {
    int k = k0 + ct * 16 + l15;
    float bv = bias[k];
#pragma unroll
    for (int r = 0; r < 4; ++r) {
      int i = i0 + wv * 16 + quad * 4 + r;
      out[((size_t)b * 4096 + i) * 512 + k] = (f16)(acc[ct][r] + bv);
    }
  }
}

// ---------------------------------------------------------------------------
// conv_vt: val = bias[k] + sum_c wm[k][c] * in[b][c][i]
//   VT[b][k][i]=fp16(val); VT[b][512+k][i]=hi(val^2); VT[b][1024+k][i]=lo
// D rows = k (A = wm direct), D cols = i (B = staged in-tile).
// ---------------------------------------------------------------------------
__global__ __launch_bounds__(256, 2) void conv_vt(
    const float* __restrict__ in, const float* __restrict__ wm,
    const float* __restrict__ bias, f16* __restrict__ vt) {
  const int i0 = blockIdx.x * 64;
  const int k0 = blockIdx.y * 64;
  const int b = blockIdx.z;
  const int tid = threadIdx.x;
  const int lane = tid & 63;
  const int wv = tid >> 6;
  const int l15 = lane & 15;
  const int quad = lane >> 4;

  __shared__ __align__(16) f16 b_lds[64 * 40];  // [i][c] stride 40

  const float* inb = in + (size_t)b * (512 * 4096);

  f32x4 acc[4];
#pragma unroll
  for (int t = 0; t < 4; ++t) acc[t] = f32x4{0.f, 0.f, 0.f, 0.f};

  for (int cs = 0; cs < 512; cs += 32) {
    __syncthreads();
#pragma unroll
    for (int rep = 0; rep < 2; ++rep) {
      int chunk = tid + rep * 256;
      int cc = chunk >> 4;
      int f4 = chunk & 15;
      float4 v = *(const float4*)(inb + (size_t)(cs + cc) * 4096 + i0 + f4 * 4);
      int ib = f4 * 4;
      b_lds[(ib + 0) * 40 + cc] = (f16)v.x;
      b_lds[(ib + 1) * 40 + cc] = (f16)v.y;
      b_lds[(ib + 2) * 40 + cc] = (f16)v.z;
      b_lds[(ib + 3) * 40 + cc] = (f16)v.w;
    }
    __syncthreads();
    const float* wp = wm + (size_t)(k0 + wv * 16 + l15) * 512 + cs + quad * 8;
    float4 w0 = *(const float4*)wp;
    float4 w1 = *(const float4*)(wp + 4);
    f16x8 af;
    af[0] = (f16)w0.x; af[1] = (f16)w0.y; af[2] = (f16)w0.z; af[3] = (f16)w0.w;
    af[4] = (f16)w1.x; af[5] = (f16)w1.y; af[6] = (f16)w1.z; af[7] = (f16)w1.w;
#pragma unroll
    for (int ct = 0; ct < 4; ++ct) {
      f16x8 bfr = *(const f16x8*)&b_lds[(ct * 16 + l15) * 40 + quad * 8];
      acc[ct] = __builtin_amdgcn_mfma_f32_16x16x32_f16(af, bfr, acc[ct], 0, 0, 0);
    }
  }
  f16* vtb = vt + (size_t)b * 1536 * 4096;
#pragma unroll
  for (int ct = 0; ct < 4; ++ct) {
    int i = i0 + ct * 16 + l15;
#pragma unroll
    for (int r = 0; r < 4; ++r) {
      int k = k0 + wv * 16 + quad * 4 + r;
      float val = acc[ct][r] + bias[k];
      f16 vh = (f16)val;
      float vf = (float)vh;
      float sq = vf * vf;
      f16 sqh = (f16)sq;
      f16 sql = (f16)(sq - (float)sqh);
      vtb[(size_t)k * 4096 + i] = vh;
      vtb[(size_t)(512 + k) * 4096 + i] = sqh;
      vtb[(size_t)(1024 + k) * 4096 + i] = sql;
    }
  }
}

// ---------------------------------------------------------------------------
// adaattn_flash: per block = 16 Q-rows of one batch; 4 waves; M-tiles of 64.
//   wave w owns V cols [w*384, w*384+384) (24 16x16 acc tiles, 96 AGPRs).
//   F frags preloaded (64 VGPRs). G staged via global_load_lds. V direct.
// ---------------------------------------------------------------------------
__global__ __launch_bounds__(256, 2) void adaattn_flash(
    const f16* __restrict__ Fb, const f16* __restrict__ Gb,
    const f16* __restrict__ VT, const float* __restrict__ cx,
    float* __restrict__ out) {
  const int n0 = blockIdx.x * 16;
  const int b = blockIdx.y;
  const int tid = threadIdx.x;
  const int lane = tid & 63;
  const int wv = tid >> 6;
  const int l15 = lane & 15;
  const int quad = lane >> 4;

  // union: main phase g_lds(66560)+p_lds(2304)+smax(256)+ssum(256) = 69376 B
  //        epilogue  meanL(36864)+e2L(36864) = 73728 B
  __shared__ __align__(16) char smem[73728];
  f16* g_lds = (f16*)smem;                 // [64][520] fp16
  f16* p_lds = (f16*)(smem + 66560);       // [16][72] fp16
  float* smax = (float*)(smem + 68864);    // [4][16]
  float* ssum = (float*)(smem + 69120);    // [4][16]

  // preload F fragments: A[m=l15][k=quad*8+j], 16 K-steps of 32
  f16x8 ffrag[16];
  {
    const f16* fp = Fb + ((size_t)b * 4096 + n0 + l15) * 512 + quad * 8;
#pragma unroll
    for (int ks = 0; ks < 16; ++ks) ffrag[ks] = *(const f16x8*)(fp + ks * 32);
  }

  f32x4 acc[24];
#pragma unroll
  for (int t = 0; t < 24; ++t) acc[t] = f32x4{0.f, 0.f, 0.f, 0.f};
  float m_run[4] = {-1e30f, -1e30f, -1e30f, -1e30f};
  float l_run[4] = {0.f, 0.f, 0.f, 0.f};

  const f16* gb = Gb + (size_t)b * 4096 * 512;
  const f16* vb = VT + ((size_t)b * 1536 + (size_t)wv * 384 + l15) * 4096;

  for (int m0 = 0; m0 < 4096; m0 += 64) {
    __syncthreads();
    {  // stage G rows m0..m0+63 (each row = 1KB = one wave-issue of 16B x 64)
      const f16* gsrc = gb + (size_t)(m0 + wv * 16) * 512 + lane * 8;
#pragma unroll
      for (int rr = 0; rr < 16; ++rr)
        async_load16(gsrc + (size_t)rr * 512, &g_lds[(wv * 16 + rr) * 520]);
    }
    __syncthreads();

    // QK: wave w -> logit cols [w*16, w*16+16), K=512
    f32x4 lg = f32x4{0.f, 0.f, 0.f, 0.f};
    {
      const f16* gl = &g_lds[(wv * 16 + l15) * 520 + quad * 8];
#pragma unroll
      for (int ks = 0; ks < 16; ++ks) {
        f16x8 gf = *(const f16x8*)(gl + ks * 32);
        lg = __builtin_amdgcn_mfma_f32_16x16x32_f16(ffrag[ks], gf, lg, 0, 0, 0);
      }
    }

    // wave-local row max over 16 cols (butterfly within 16-lane groups)
    float tm[4];
#pragma unroll
    for (int r = 0; r < 4; ++r) {
      float v = lg[r];
      v = fmaxf(v, __shfl_xor(v, 1));
      v = fmaxf(v, __shfl_xor(v, 2));
      v = fmaxf(v, __shfl_xor(v, 4));
      v = fmaxf(v, __shfl_xor(v, 8));
      tm[r] = v;
    }
    if (l15 == 0) {
#pragma unroll
      for (int r = 0; r < 4; ++r) smax[wv * 16 + quad * 4 + r] = tm[r];
    }
    __syncthreads();

    float alpha[4], ts[4];
#pragma unroll
    for (int r = 0; r < 4; ++r) {
      int row = quad * 4 + r;
      float mt = fmaxf(fmaxf(smax[row], smax[16 + row]),
                       fmaxf(smax[32 + row], smax[48 + row]));
      float mn = fmaxf(m_run[r], mt);
      alpha[r] = exp2f((m_run[r] - mn) * LOG2E);
      m_run[r] = mn;
      float p = exp2f((lg[r] - mn) * LOG2E);
      f16 ph = (f16)p;     // round first so weights & sums agree exactly
      p = (float)ph;
      p_lds[row * 72 + wv * 16 + l15] = ph;
      float s = p;
      s += __shfl_xor(s, 1);
      s += __shfl_xor(s, 2);
      s += __shfl_xor(s, 4);
      s += __shfl_xor(s, 8);
      ts[r] = s;
    }
    if (l15 == 0) {
#pragma unroll
      for (int r = 0; r < 4; ++r) ssum[wv * 16 + quad * 4 + r] = ts[r];
    }
    // rescale accumulators by alpha (per-row)
#pragma unroll
    for (int t = 0; t < 24; ++t) {
#pragma unroll
      for (int r = 0; r < 4; ++r) acc[t][r] *= alpha[r];
    }
    __syncthreads();

#pragma unroll
    for (int r = 0; r < 4; ++r) {
      int row = quad * 4 + r;
      l_run[r] = l_run[r] * alpha[r] +
                 (ssum[row] + ssum[16 + row] + ssum[32 + row] + ssum[48 + row]);
    }

    // PV: A = P (from LDS), B = VT rows direct from global (L3-resident)
    f16x8 pf0 = *(const f16x8*)&p_lds[l15 * 72 + quad * 8];
    f16x8 pf1 = *(const f16x8*)&p_lds[l15 * 72 + 32 + quad * 8];
    const f16* vp = vb + m0 + quad * 8;
#pragma unroll 8
    for (int ct = 0; ct < 24; ++ct) {
      f16x8 v0 = *(const f16x8*)(vp + (size_t)ct * (16 * 4096));
      f16x8 v1 = *(const f16x8*)(vp + (size_t)ct * (16 * 4096) + 32);
      acc[ct] = __builtin_amdgcn_mfma_f32_16x16x32_f16(pf0, v0, acc[ct], 0, 0, 0);
      acc[ct] = __builtin_amdgcn_mfma_f32_16x16x32_f16(pf1, v1, acc[ct], 0, 0, 0);
    }
  }

  // ---------------- epilogue ----------------
  __syncthreads();  // all p_lds/g_lds reads done before aliasing as meanL/e2L
  float inv[4];
#pragma unroll
  for (int r = 0; r < 4; ++r) inv[r] = 1.0f / l_run[r];

  float* meanL = (float*)smem;           // [512][18]
  float* e2L = (float*)(smem + 36864);   // [512][18]

  // phase 1: write mean (grp 0) and e2-hi (grp 1)
#pragma unroll
  for (int ct = 0; ct < 24; ++ct) {
    int vcol = wv * 384 + ct * 16 + l15;
    int grp = vcol >> 9;
    int c = vcol & 511;
    if (grp < 2) {
      float* dst = (grp == 0) ? meanL : e2L;
#pragma unroll
      for (int r = 0; r < 4; ++r) dst[c * 18 + quad * 4 + r] = acc[ct][r] * inv[r];
    }
  }
  __syncthreads();
  // phase 2: add e2-lo (grp 2)
#pragma unroll
  for (int ct = 0; ct < 24; ++ct) {
    int vcol = wv * 384 + ct * 16 + l15;
    int grp = vcol >> 9;
    int c = vcol & 511;
    if (grp == 2) {
#pragma unroll
      for (int r = 0; r < 4; ++r) e2L[c * 18 + quad * 4 + r] += acc[ct][r] * inv[r];
    }
  }
  __syncthreads();

  // final: out[b][c][n0+nl] = std * c_x + mean
#pragma unroll 4
  for (int rep = 0; rep < 32; ++rep) {
    int idx = tid + rep * 256;
    int c = idx >> 4;
    int nl = idx & 15;
    float m = meanL[c * 18 + nl];
    float e2v = e2L[c * 18 + nl];
    float sd = sqrtf(fmaxf(e2v - m * m, 0.f));
    size_t gi = ((size_t)b * 512 + c) * 4096 + n0 + nl;
    out[gi] = sd * cx[gi] + m;
  }
}

// ---------------------------------------------------------------------------
extern "C" void kernel_launch(void* const* d_in, const int* in_sizes, int n_in,
                              void* d_out, int out_size, void* d_ws, size_t ws_size,
                              hipStream_t stream) {
  (void)in_sizes; (void)n_in; (void)out_size;
  const float* c_x  = (const float*)d_in[0];
  const float* s_x  = (const float*)d_in[1];
  const float* c_1x = (const float*)d_in[2];
  const float* s_1x = (const float*)d_in[3];
  const float* f_w  = (const float*)d_in[4];
  const float* f_b  = (const float*)d_in[5];
  const float* g_w  = (const float*)d_in[6];
  const float* g_b  = (const float*)d_in[7];
  const float* h_w  = (const float*)d_in[8];
  const float* h_b  = (const float*)d_in[9];
  float* out = (float*)d_out;

  const size_t fe = (size_t)4 * 4096 * 512;  // elements per F/G buffer
  f16* Fb = (f16*)d_ws;
  f16* Gb = Fb + fe;
  f16* VT = Gb + fe;
  const size_t need = fe * 2 * sizeof(f16) * 2 + (size_t)4 * 1536 * 4096 * sizeof(f16);
  if (ws_size < need) return;  // 80 MiB required; fail loudly (output stays poisoned)

  dim3 blk(256);
  dim3 gP(64, 8, 4);
  conv_ik<<<gP, blk, 0, stream>>>(c_1x, f_w, f_b, Fb);
  conv_ik<<<gP, blk, 0, stream>>>(s_1x, g_w, g_b, Gb);
  conv_vt<<<gP, blk, 0, stream>>>(s_x, h_w, h_b, VT);
  adaattn_flash<<<dim3(256, 4), blk, 0, stream>>>(Fb, Gb, VT, c_x, out);
}

// Round 2
// 4369.964 us; speedup vs baseline: 1.0533x; 1.0533x over previous
//
#include <hip/hip_runtime.h>
#include <cstdint>
#include <cstddef>

// ---------------------------------------------------------------------------
// AdaAttN fused kernel set, fp16 MFMA path.
//   B=4, C=KP=512, N=M=4096.
//   ws layout (fp16): Fb[4][4096][512] | Gb[4][4096][512] | VT[4][1536][4096]
//     VT rows per batch: [0..511]   = Hs (v-hat, fp16)
//                        [512..1023]= fp16(v-hat^2)   (hi)
//                        [1024..1535]= v-hat^2 - hi    (lo)  -- protects e2-mean^2
//
// R2: flash kernel de-spilled. R1 had 96 acc + 64 persistent ffrag + 64
// transient PV-load regs > 256/wave cap -> acc spilled to scratch ->
// 12.9 GB/dispatch scratch writes (== WRITE_SIZE) -> 4.5 ms memory-bound.
// Fix: F fragments read直接 from global per QK step (16 KB tile, L1-hot),
// rescale guarded by wave-uniform __any(alpha!=1).
// ---------------------------------------------------------------------------

typedef _Float16 f16;
typedef _Float16 f16x8 __attribute__((ext_vector_type(8)));
typedef float f32x4 __attribute__((ext_vector_type(4)));

#define LOG2E 1.44269504088896340736f

__device__ __forceinline__ void async_load16(const void* g, void* l) {
  // global -> LDS direct DMA, 16B per lane; LDS dest = uniform base + lane*16
  __builtin_amdgcn_global_load_lds((const __attribute__((address_space(1))) void*)g,
                                   (__attribute__((address_space(3))) void*)l,
                                   16, 0, 0);
}

// ---------------------------------------------------------------------------
// conv_ik: out[b][i][k] = bias[k] + sum_c wm[k][c] * in[b][c][i]   (fp16 out)
// ---------------------------------------------------------------------------
__global__ __launch_bounds__(256, 2) void conv_ik(
    const float* __restrict__ in, const float* __restrict__ wm,
    const float* __restrict__ bias, f16* __restrict__ out) {
  const int i0 = blockIdx.x * 64;
  const int k0 = blockIdx.y * 64;
  const int b = blockIdx.z;
  const int tid = threadIdx.x;
  const int lane = tid & 63;
  const int wv = tid >> 6;
  const int l15 = lane & 15;
  const int quad = lane >> 4;

  __shared__ __align__(16) f16 a_lds[64 * 40];  // [i][c] stride 40 (pad)

  const float* inb = in + (size_t)b * (512 * 4096);

  f32x4 acc[4];
#pragma unroll
  for (int t = 0; t < 4; ++t) acc[t] = f32x4{0.f, 0.f, 0.f, 0.f};

  for (int cs = 0; cs < 512; cs += 32) {
    __syncthreads();
#pragma unroll
    for (int rep = 0; rep < 2; ++rep) {
      int chunk = tid + rep * 256;  // 0..511
      int cc = chunk >> 4;          // 0..31
      int f4 = chunk & 15;          // 0..15
      float4 v = *(const float4*)(inb + (size_t)(cs + cc) * 4096 + i0 + f4 * 4);
      int ib = f4 * 4;
      a_lds[(ib + 0) * 40 + cc] = (f16)v.x;
      a_lds[(ib + 1) * 40 + cc] = (f16)v.y;
      a_lds[(ib + 2) * 40 + cc] = (f16)v.z;
      a_lds[(ib + 3) * 40 + cc] = (f16)v.w;
    }
    __syncthreads();
    f16x8 af = *(const f16x8*)&a_lds[(wv * 16 + l15) * 40 + quad * 8];
#pragma unroll
    for (int ct = 0; ct < 4; ++ct) {
      const float* wp = wm + (size_t)(k0 + ct * 16 + l15) * 512 + cs + quad * 8;
      float4 w0 = *(const float4*)wp;
      float4 w1 = *(const float4*)(wp + 4);
      f16x8 bf;
      bf[0] = (f16)w0.x; bf[1] = (f16)w0.y; bf[2] = (f16)w0.z; bf[3] = (f16)w0.w;
      bf[4] = (f16)w1.x; bf[5] = (f16)w1.y; bf[6] = (f16)w1.z; bf[7] = (f16)w1.w;
      acc[ct] = __builtin_amdgcn_mfma_f32_16x16x32_f16(af, bf, acc[ct], 0, 0, 0);
    }
  }
#pragma unroll
  for (int ct = 0; ct < 4; ++ct) {
    int k = k0 + ct * 16 + l15;
    float bv = bias[k];
#pragma unroll
    for (int r = 0; r < 4; ++r) {
      int i = i0 + wv * 16 + quad * 4 + r;
      out[((size_t)b * 4096 + i) * 512 + k] = (f16)(acc[ct][r] + bv);
    }
  }
}

// ---------------------------------------------------------------------------
// conv_vt: val = bias[k] + sum_c wm[k][c] * in[b][c][i]
//   VT[b][k][i]=fp16(val); VT[b][512+k][i]=hi(val^2); VT[b][1024+k][i]=lo
// ---------------------------------------------------------------------------
__global__ __launch_bounds__(256, 2) void conv_vt(
    const float* __restrict__ in, const float* __restrict__ wm,
    const float* __restrict__ bias, f16* __restrict__ vt) {
  const int i0 = blockIdx.x * 64;
  const int k0 = blockIdx.y * 64;
  const int b = blockIdx.z;
  const int tid = threadIdx.x;
  const int lane = tid & 63;
  const int wv = tid >> 6;
  const int l15 = lane & 15;
  const int quad = lane >> 4;

  __shared__ __align__(16) f16 b_lds[64 * 40];  // [i][c] stride 40

  const float* inb = in + (size_t)b * (512 * 4096);

  f32x4 acc[4];
#pragma unroll
  for (int t = 0; t < 4; ++t) acc[t] = f32x4{0.f, 0.f, 0.f, 0.f};

  for (int cs = 0; cs < 512; cs += 32) {
    __syncthreads();
#pragma unroll
    for (int rep = 0; rep < 2; ++rep) {
      int chunk = tid + rep * 256;
      int cc = chunk >> 4;
      int f4 = chunk & 15;
      float4 v = *(const float4*)(inb + (size_t)(cs + cc) * 4096 + i0 + f4 * 4);
      int ib = f4 * 4;
      b_lds[(ib + 0) * 40 + cc] = (f16)v.x;
      b_lds[(ib + 1) * 40 + cc] = (f16)v.y;
      b_lds[(ib + 2) * 40 + cc] = (f16)v.z;
      b_lds[(ib + 3) * 40 + cc] = (f16)v.w;
    }
    __syncthreads();
    const float* wp = wm + (size_t)(k0 + wv * 16 + l15) * 512 + cs + quad * 8;
    float4 w0 = *(const float4*)wp;
    float4 w1 = *(const float4*)(wp + 4);
    f16x8 af;
    af[0] = (f16)w0.x; af[1] = (f16)w0.y; af[2] = (f16)w0.z; af[3] = (f16)w0.w;
    af[4] = (f16)w1.x; af[5] = (f16)w1.y; af[6] = (f16)w1.z; af[7] = (f16)w1.w;
#pragma unroll
    for (int ct = 0; ct < 4; ++ct) {
      f16x8 bfr = *(const f16x8*)&b_lds[(ct * 16 + l15) * 40 + quad * 8];
      acc[ct] = __builtin_amdgcn_mfma_f32_16x16x32_f16(af, bfr, acc[ct], 0, 0, 0);
    }
  }
  f16* vtb = vt + (size_t)b * 1536 * 4096;
#pragma unroll
  for (int ct = 0; ct < 4; ++ct) {
    int i = i0 + ct * 16 + l15;
#pragma unroll
    for (int r = 0; r < 4; ++r) {
      int k = k0 + wv * 16 + quad * 4 + r;
      float val = acc[ct][r] + bias[k];
      f16 vh = (f16)val;
      float vf = (float)vh;
      float sq = vf * vf;
      f16 sqh = (f16)sq;
      f16 sql = (f16)(sq - (float)sqh);
      vtb[(size_t)k * 4096 + i] = vh;
      vtb[(size_t)(512 + k) * 4096 + i] = sqh;
      vtb[(size_t)(1024 + k) * 4096 + i] = sql;
    }
  }
}

// ---------------------------------------------------------------------------
// adaattn_flash: per block = 16 Q-rows of one batch; 4 waves; M-tiles of 64.
//   wave w owns V cols [w*384, w*384+384) (24 16x16 acc tiles, 96 AGPRs).
//   F fragments read directly from global (16 KB tile, L1-resident).
//   G staged via global_load_lds. V direct from global (L2/L3-resident).
// ---------------------------------------------------------------------------
__global__ __launch_bounds__(256, 2) void adaattn_flash(
    const f16* __restrict__ Fb, const f16* __restrict__ Gb,
    const f16* __restrict__ VT, const float* __restrict__ cx,
    float* __restrict__ out) {
  const int n0 = blockIdx.x * 16;
  const int b = blockIdx.y;
  const int tid = threadIdx.x;
  const int lane = tid & 63;
  const int wv = tid >> 6;
  const int l15 = lane & 15;
  const int quad = lane >> 4;

  // union: main phase g_lds(66560)+p_lds(2304)+smax(256)+ssum(256) = 69376 B
  //        epilogue  meanL(36864)+e2L(36864) = 73728 B
  __shared__ __align__(16) char smem[73728];
  f16* g_lds = (f16*)smem;                 // [64][520] fp16
  f16* p_lds = (f16*)(smem + 66560);       // [16][72] fp16
  float* smax = (float*)(smem + 68864);    // [4][16]
  float* ssum = (float*)(smem + 69120);    // [4][16]

  // F A-fragment base: A[m=l15][k=quad*8+j]; re-read per K-step (L1-hot)
  const f16* fp = Fb + ((size_t)b * 4096 + n0 + l15) * 512 + quad * 8;

  f32x4 acc[24];
#pragma unroll
  for (int t = 0; t < 24; ++t) acc[t] = f32x4{0.f, 0.f, 0.f, 0.f};
  float m_run[4] = {-1e30f, -1e30f, -1e30f, -1e30f};
  float l_run[4] = {0.f, 0.f, 0.f, 0.f};

  const f16* gb = Gb + (size_t)b * 4096 * 512;
  const f16* vb = VT + ((size_t)b * 1536 + (size_t)wv * 384 + l15) * 4096;

  for (int m0 = 0; m0 < 4096; m0 += 64) {
    __syncthreads();
    {  // stage G rows m0..m0+63 (each row = 1KB = one wave-issue of 16B x 64)
      const f16* gsrc = gb + (size_t)(m0 + wv * 16) * 512 + lane * 8;
#pragma unroll
      for (int rr = 0; rr < 16; ++rr)
        async_load16(gsrc + (size_t)rr * 512, &g_lds[(wv * 16 + rr) * 520]);
    }
    __syncthreads();

    // QK: wave w -> logit cols [w*16, w*16+16), K=512
    f32x4 lg = f32x4{0.f, 0.f, 0.f, 0.f};
    {
      const f16* gl = &g_lds[(wv * 16 + l15) * 520 + quad * 8];
#pragma unroll 8
      for (int ks = 0; ks < 16; ++ks) {
        f16x8 gf = *(const f16x8*)(gl + ks * 32);
        f16x8 ff = *(const f16x8*)(fp + ks * 32);
        lg = __builtin_amdgcn_mfma_f32_16x16x32_f16(ff, gf, lg, 0, 0, 0);
      }
    }

    // wave-local row max over 16 cols (butterfly within 16-lane groups)
    float tm[4];
#pragma unroll
    for (int r = 0; r < 4; ++r) {
      float v = lg[r];
      v = fmaxf(v, __shfl_xor(v, 1));
      v = fmaxf(v, __shfl_xor(v, 2));
      v = fmaxf(v, __shfl_xor(v, 4));
      v = fmaxf(v, __shfl_xor(v, 8));
      tm[r] = v;
    }
    if (l15 == 0) {
#pragma unroll
      for (int r = 0; r < 4; ++r) smax[wv * 16 + quad * 4 + r] = tm[r];
    }
    __syncthreads();

    float alpha[4], ts[4];
#pragma unroll
    for (int r = 0; r < 4; ++r) {
      int row = quad * 4 + r;
      float mt = fmaxf(fmaxf(smax[row], smax[16 + row]),
                       fmaxf(smax[32 + row], smax[48 + row]));
      float mn = fmaxf(m_run[r], mt);
      alpha[r] = exp2f((m_run[r] - mn) * LOG2E);
      m_run[r] = mn;
      float p = exp2f((lg[r] - mn) * LOG2E);
      f16 ph = (f16)p;     // round first so weights & sums agree exactly
      p = (float)ph;
      p_lds[row * 72 + wv * 16 + l15] = ph;
      float s = p;
      s += __shfl_xor(s, 1);
      s += __shfl_xor(s, 2);
      s += __shfl_xor(s, 4);
      s += __shfl_xor(s, 8);
      ts[r] = s;
    }
    if (l15 == 0) {
#pragma unroll
      for (int r = 0; r < 4; ++r) ssum[wv * 16 + quad * 4 + r] = ts[r];
    }
    // rescale accumulators by alpha (per-row); skip when all alpha == 1
    // (exact identity -> numerics unchanged; max updates are rare after the
    //  first few tiles, saves 96 VALU mults/lane/iter)
    if (__any(alpha[0] != 1.f || alpha[1] != 1.f ||
              alpha[2] != 1.f || alpha[3] != 1.f)) {
#pragma unroll
      for (int t = 0; t < 24; ++t) {
#pragma unroll
        for (int r = 0; r < 4; ++r) acc[t][r] *= alpha[r];
      }
    }
    __syncthreads();

#pragma unroll
    for (int r = 0; r < 4; ++r) {
      int row = quad * 4 + r;
      l_run[r] = l_run[r] * alpha[r] +
                 (ssum[row] + ssum[16 + row] + ssum[32 + row] + ssum[48 + row]);
    }

    // PV: A = P (from LDS), B = VT rows direct from global (L2/L3-resident)
    f16x8 pf0 = *(const f16x8*)&p_lds[l15 * 72 + quad * 8];
    f16x8 pf1 = *(const f16x8*)&p_lds[l15 * 72 + 32 + quad * 8];
    const f16* vp = vb + m0 + quad * 8;
#pragma unroll 8
    for (int ct = 0; ct < 24; ++ct) {
      f16x8 v0 = *(const f16x8*)(vp + (size_t)ct * (16 * 4096));
      f16x8 v1 = *(const f16x8*)(vp + (size_t)ct * (16 * 4096) + 32);
      acc[ct] = __builtin_amdgcn_mfma_f32_16x16x32_f16(pf0, v0, acc[ct], 0, 0, 0);
      acc[ct] = __builtin_amdgcn_mfma_f32_16x16x32_f16(pf1, v1, acc[ct], 0, 0, 0);
    }
  }

  // ---------------- epilogue ----------------
  __syncthreads();  // all p_lds/g_lds reads done before aliasing as meanL/e2L
  float inv[4];
#pragma unroll
  for (int r = 0; r < 4; ++r) inv[r] = 1.0f / l_run[r];

  float* meanL = (float*)smem;           // [512][18]
  float* e2L = (float*)(smem + 36864);   // [512][18]

  // phase 1: write mean (grp 0) and e2-hi (grp 1)
#pragma unroll
  for (int ct = 0; ct < 24; ++ct) {
    int vcol = wv * 384 + ct * 16 + l15;
    int grp = vcol >> 9;
    int c = vcol & 511;
    if (grp < 2) {
      float* dst = (grp == 0) ? meanL : e2L;
#pragma unroll
      for (int r = 0; r < 4; ++r) dst[c * 18 + quad * 4 + r] = acc[ct][r] * inv[r];
    }
  }
  __syncthreads();
  // phase 2: add e2-lo (grp 2)
#pragma unroll
  for (int ct = 0; ct < 24; ++ct) {
    int vcol = wv * 384 + ct * 16 + l15;
    int grp = vcol >> 9;
    int c = vcol & 511;
    if (grp == 2) {
#pragma unroll
      for (int r = 0; r < 4; ++r) e2L[c * 18 + quad * 4 + r] += acc[ct][r] * inv[r];
    }
  }
  __syncthreads();

  // final: out[b][c][n0+nl] = std * c_x + mean
#pragma unroll 4
  for (int rep = 0; rep < 32; ++rep) {
    int idx = tid + rep * 256;
    int c = idx >> 4;
    int nl = idx & 15;
    float m = meanL[c * 18 + nl];
    float e2v = e2L[c * 18 + nl];
    float sd = sqrtf(fmaxf(e2v - m * m, 0.f));
    size_t gi = ((size_t)b * 512 + c) * 4096 + n0 + nl;
    out[gi] = sd * cx[gi] + m;
  }
}

// ---------------------------------------------------------------------------
extern "C" void kernel_launch(void* const* d_in, const int* in_sizes, int n_in,
                              void* d_out, int out_size, void* d_ws, size_t ws_size,
                              hipStream_t stream) {
  (void)in_sizes; (void)n_in; (void)out_size;
  const float* c_x  = (const float*)d_in[0];
  const float* s_x  = (const float*)d_in[1];
  const float* c_1x = (const float*)d_in[2];
  const float* s_1x = (const float*)d_in[3];
  const float* f_w  = (const float*)d_in[4];
  const float* f_b  = (const float*)d_in[5];
  const float* g_w  = (const float*)d_in[6];
  const float* g_b  = (const float*)d_in[7];
  const float* h_w  = (const float*)d_in[8];
  const float* h_b  = (const float*)d_in[9];
  float* out = (float*)d_out;

  const size_t fe = (size_t)4 * 4096 * 512;  // elements per F/G buffer
  f16* Fb = (f16*)d_ws;
  f16* Gb = Fb + fe;
  f16* VT = Gb + fe;
  const size_t need = fe * 2 * sizeof(f16) * 2 + (size_t)4 * 1536 * 4096 * sizeof(f16);
  if (ws_size < need) return;  // 80 MiB required; fail loudly (output stays poisoned)

  dim3 blk(256);
  dim3 gP(64, 8, 4);
  conv_ik<<<gP, blk, 0, stream>>>(c_1x, f_w, f_b, Fb);
  conv_ik<<<gP, blk, 0, stream>>>(s_1x, g_w, g_b, Gb);
  conv_vt<<<gP, blk, 0, stream>>>(s_x, h_w, h_b, VT);
  adaattn_flash<<<dim3(256, 4), blk, 0, stream>>>(Fb, Gb, VT, c_x, out);
}

// Round 3
// 2445.450 us; speedup vs baseline: 1.8822x; 1.7870x over previous
//
#include <hip/hip_runtime.h>
#include <cstdint>
#include <cstddef>

// ---------------------------------------------------------------------------
// AdaAttN fused kernel set, fp16 MFMA path.
//   B=4, C=KP=512, N=M=4096.
//   ws layout (fp16): Fb[4][4096][512] | Gb[4][4096][512] | VT[4][1536][4096]
//     VT rows per batch: [0..511]   = Hs (v-hat, fp16)
//                        [512..1023]= fp16(v-hat^2)   (hi)
//                        [1024..1535]= v-hat^2 - hi    (lo)  -- protects e2-mean^2
//
// R3: THE fix. R1/R2's `#pragma unroll 8` on the 24-iter PV loop was a
// PARTIAL unroll -> runtime `ct` -> acc[ct] dynamically indexed -> LLVM
// demoted acc[24] to scratch -> every MFMA did scratch C-load/D-store
// (9.4 GB WRITE_SIZE/dispatch, the whole 4.2 ms). Full unroll makes every
// acc index a constant so acc lives in the unified VGPR/AGPR file.
// ---------------------------------------------------------------------------

typedef _Float16 f16;
typedef _Float16 f16x8 __attribute__((ext_vector_type(8)));
typedef float f32x4 __attribute__((ext_vector_type(4)));

#define LOG2E 1.44269504088896340736f

__device__ __forceinline__ void async_load16(const void* g, void* l) {
  // global -> LDS direct DMA, 16B per lane; LDS dest = uniform base + lane*16
  __builtin_amdgcn_global_load_lds((const __attribute__((address_space(1))) void*)g,
                                   (__attribute__((address_space(3))) void*)l,
                                   16, 0, 0);
}

// ---------------------------------------------------------------------------
// conv_ik: out[b][i][k] = bias[k] + sum_c wm[k][c] * in[b][c][i]   (fp16 out)
// ---------------------------------------------------------------------------
__global__ __launch_bounds__(256, 2) void conv_ik(
    const float* __restrict__ in, const float* __restrict__ wm,
    const float* __restrict__ bias, f16* __restrict__ out) {
  const int i0 = blockIdx.x * 64;
  const int k0 = blockIdx.y * 64;
  const int b = blockIdx.z;
  const int tid = threadIdx.x;
  const int lane = tid & 63;
  const int wv = tid >> 6;
  const int l15 = lane & 15;
  const int quad = lane >> 4;

  __shared__ __align__(16) f16 a_lds[64 * 40];  // [i][c] stride 40 (pad)

  const float* inb = in + (size_t)b * (512 * 4096);

  f32x4 acc[4];
#pragma unroll
  for (int t = 0; t < 4; ++t) acc[t] = f32x4{0.f, 0.f, 0.f, 0.f};

  for (int cs = 0; cs < 512; cs += 32) {
    __syncthreads();
#pragma unroll
    for (int rep = 0; rep < 2; ++rep) {
      int chunk = tid + rep * 256;  // 0..511
      int cc = chunk >> 4;          // 0..31
      int f4 = chunk & 15;          // 0..15
      float4 v = *(const float4*)(inb + (size_t)(cs + cc) * 4096 + i0 + f4 * 4);
      int ib = f4 * 4;
      a_lds[(ib + 0) * 40 + cc] = (f16)v.x;
      a_lds[(ib + 1) * 40 + cc] = (f16)v.y;
      a_lds[(ib + 2) * 40 + cc] = (f16)v.z;
      a_lds[(ib + 3) * 40 + cc] = (f16)v.w;
    }
    __syncthreads();
    f16x8 af = *(const f16x8*)&a_lds[(wv * 16 + l15) * 40 + quad * 8];
#pragma unroll
    for (int ct = 0; ct < 4; ++ct) {
      const float* wp = wm + (size_t)(k0 + ct * 16 + l15) * 512 + cs + quad * 8;
      float4 w0 = *(const float4*)wp;
      float4 w1 = *(const float4*)(wp + 4);
      f16x8 bf;
      bf[0] = (f16)w0.x; bf[1] = (f16)w0.y; bf[2] = (f16)w0.z; bf[3] = (f16)w0.w;
      bf[4] = (f16)w1.x; bf[5] = (f16)w1.y; bf[6] = (f16)w1.z; bf[7] = (f16)w1.w;
      acc[ct] = __builtin_amdgcn_mfma_f32_16x16x32_f16(af, bf, acc[ct], 0, 0, 0);
    }
  }
#pragma unroll
  for (int ct = 0; ct < 4; ++ct) {
    int k = k0 + ct * 16 + l15;
    float bv = bias[k];
#pragma unroll
    for (int r = 0; r < 4; ++r) {
      int i = i0 + wv * 16 + quad * 4 + r;
      out[((size_t)b * 4096 + i) * 512 + k] = (f16)(acc[ct][r] + bv);
    }
  }
}

// ---------------------------------------------------------------------------
// conv_vt: val = bias[k] + sum_c wm[k][c] * in[b][c][i]
//   VT[b][k][i]=fp16(val); VT[b][512+k][i]=hi(val^2); VT[b][1024+k][i]=lo
// ---------------------------------------------------------------------------
__global__ __launch_bounds__(256, 2) void conv_vt(
    const float* __restrict__ in, const float* __restrict__ wm,
    const float* __restrict__ bias, f16* __restrict__ vt) {
  const int i0 = blockIdx.x * 64;
  const int k0 = blockIdx.y * 64;
  const int b = blockIdx.z;
  const int tid = threadIdx.x;
  const int lane = tid & 63;
  const int wv = tid >> 6;
  const int l15 = lane & 15;
  const int quad = lane >> 4;

  __shared__ __align__(16) f16 b_lds[64 * 40];  // [i][c] stride 40

  const float* inb = in + (size_t)b * (512 * 4096);

  f32x4 acc[4];
#pragma unroll
  for (int t = 0; t < 4; ++t) acc[t] = f32x4{0.f, 0.f, 0.f, 0.f};

  for (int cs = 0; cs < 512; cs += 32) {
    __syncthreads();
#pragma unroll
    for (int rep = 0; rep < 2; ++rep) {
      int chunk = tid + rep * 256;
      int cc = chunk >> 4;
      int f4 = chunk & 15;
      float4 v = *(const float4*)(inb + (size_t)(cs + cc) * 4096 + i0 + f4 * 4);
      int ib = f4 * 4;
      b_lds[(ib + 0) * 40 + cc] = (f16)v.x;
      b_lds[(ib + 1) * 40 + cc] = (f16)v.y;
      b_lds[(ib + 2) * 40 + cc] = (f16)v.z;
      b_lds[(ib + 3) * 40 + cc] = (f16)v.w;
    }
    __syncthreads();
    const float* wp = wm + (size_t)(k0 + wv * 16 + l15) * 512 + cs + quad * 8;
    float4 w0 = *(const float4*)wp;
    float4 w1 = *(const float4*)(wp + 4);
    f16x8 af;
    af[0] = (f16)w0.x; af[1] = (f16)w0.y; af[2] = (f16)w0.z; af[3] = (f16)w0.w;
    af[4] = (f16)w1.x; af[5] = (f16)w1.y; af[6] = (f16)w1.z; af[7] = (f16)w1.w;
#pragma unroll
    for (int ct = 0; ct < 4; ++ct) {
      f16x8 bfr = *(const f16x8*)&b_lds[(ct * 16 + l15) * 40 + quad * 8];
      acc[ct] = __builtin_amdgcn_mfma_f32_16x16x32_f16(af, bfr, acc[ct], 0, 0, 0);
    }
  }
  f16* vtb = vt + (size_t)b * 1536 * 4096;
#pragma unroll
  for (int ct = 0; ct < 4; ++ct) {
    int i = i0 + ct * 16 + l15;
#pragma unroll
    for (int r = 0; r < 4; ++r) {
      int k = k0 + wv * 16 + quad * 4 + r;
      float val = acc[ct][r] + bias[k];
      f16 vh = (f16)val;
      float vf = (float)vh;
      float sq = vf * vf;
      f16 sqh = (f16)sq;
      f16 sql = (f16)(sq - (float)sqh);
      vtb[(size_t)k * 4096 + i] = vh;
      vtb[(size_t)(512 + k) * 4096 + i] = sqh;
      vtb[(size_t)(1024 + k) * 4096 + i] = sql;
    }
  }
}

// ---------------------------------------------------------------------------
// adaattn_flash: per block = 16 Q-rows of one batch; 4 waves; M-tiles of 64.
//   wave w owns V cols [w*384, w*384+384) (24 16x16 acc tiles, 96 regs).
//   F fragments read directly from global (16 KB tile, L1-resident).
//   G staged via global_load_lds. V direct from global (L2/L3-resident).
//   NOTE: every loop touching acc[] MUST be fully unrolled — a partial
//   unroll leaves a runtime index and demotes acc to scratch (R1/R2 bug).
// ---------------------------------------------------------------------------
__global__ __launch_bounds__(256, 2) void adaattn_flash(
    const f16* __restrict__ Fb, const f16* __restrict__ Gb,
    const f16* __restrict__ VT, const float* __restrict__ cx,
    float* __restrict__ out) {
  const int n0 = blockIdx.x * 16;
  const int b = blockIdx.y;
  const int tid = threadIdx.x;
  const int lane = tid & 63;
  const int wv = tid >> 6;
  const int l15 = lane & 15;
  const int quad = lane >> 4;

  // union: main phase g_lds(66560)+p_lds(2304)+smax(256)+ssum(256) = 69376 B
  //        epilogue  meanL(36864)+e2L(36864) = 73728 B
  __shared__ __align__(16) char smem[73728];
  f16* g_lds = (f16*)smem;                 // [64][520] fp16
  f16* p_lds = (f16*)(smem + 66560);       // [16][72] fp16
  float* smax = (float*)(smem + 68864);    // [4][16]
  float* ssum = (float*)(smem + 69120);    // [4][16]

  // F A-fragment base: A[m=l15][k=quad*8+j]; re-read per K-step (L1-hot)
  const f16* fp = Fb + ((size_t)b * 4096 + n0 + l15) * 512 + quad * 8;

  f32x4 acc[24];
#pragma unroll
  for (int t = 0; t < 24; ++t) acc[t] = f32x4{0.f, 0.f, 0.f, 0.f};
  float m_run[4] = {-1e30f, -1e30f, -1e30f, -1e30f};
  float l_run[4] = {0.f, 0.f, 0.f, 0.f};

  const f16* gb = Gb + (size_t)b * 4096 * 512;
  const f16* vb = VT + ((size_t)b * 1536 + (size_t)wv * 384 + l15) * 4096;

  for (int m0 = 0; m0 < 4096; m0 += 64) {
    __syncthreads();
    {  // stage G rows m0..m0+63 (each row = 1KB = one wave-issue of 16B x 64)
      const f16* gsrc = gb + (size_t)(m0 + wv * 16) * 512 + lane * 8;
#pragma unroll
      for (int rr = 0; rr < 16; ++rr)
        async_load16(gsrc + (size_t)rr * 512, &g_lds[(wv * 16 + rr) * 520]);
    }
    __syncthreads();

    // QK: wave w -> logit cols [w*16, w*16+16), K=512
    f32x4 lg = f32x4{0.f, 0.f, 0.f, 0.f};
    {
      const f16* gl = &g_lds[(wv * 16 + l15) * 520 + quad * 8];
#pragma unroll 8
      for (int ks = 0; ks < 16; ++ks) {
        f16x8 gf = *(const f16x8*)(gl + ks * 32);
        f16x8 ff = *(const f16x8*)(fp + ks * 32);
        lg = __builtin_amdgcn_mfma_f32_16x16x32_f16(ff, gf, lg, 0, 0, 0);
      }
    }

    // wave-local row max over 16 cols (butterfly within 16-lane groups)
    float tm[4];
#pragma unroll
    for (int r = 0; r < 4; ++r) {
      float v = lg[r];
      v = fmaxf(v, __shfl_xor(v, 1));
      v = fmaxf(v, __shfl_xor(v, 2));
      v = fmaxf(v, __shfl_xor(v, 4));
      v = fmaxf(v, __shfl_xor(v, 8));
      tm[r] = v;
    }
    if (l15 == 0) {
#pragma unroll
      for (int r = 0; r < 4; ++r) smax[wv * 16 + quad * 4 + r] = tm[r];
    }
    __syncthreads();

    float alpha[4], ts[4];
#pragma unroll
    for (int r = 0; r < 4; ++r) {
      int row = quad * 4 + r;
      float mt = fmaxf(fmaxf(smax[row], smax[16 + row]),
                       fmaxf(smax[32 + row], smax[48 + row]));
      float mn = fmaxf(m_run[r], mt);
      alpha[r] = exp2f((m_run[r] - mn) * LOG2E);
      m_run[r] = mn;
      float p = exp2f((lg[r] - mn) * LOG2E);
      f16 ph = (f16)p;     // round first so weights & sums agree exactly
      p = (float)ph;
      p_lds[row * 72 + wv * 16 + l15] = ph;
      float s = p;
      s += __shfl_xor(s, 1);
      s += __shfl_xor(s, 2);
      s += __shfl_xor(s, 4);
      s += __shfl_xor(s, 8);
      ts[r] = s;
    }
    if (l15 == 0) {
#pragma unroll
      for (int r = 0; r < 4; ++r) ssum[wv * 16 + quad * 4 + r] = ts[r];
    }
    // rescale accumulators by alpha (per-row); skip when all alpha == 1
    // (exact identity -> numerics unchanged; max updates are rare after the
    //  first few tiles, saves 96 VALU mults/lane/iter)
    if (__any(alpha[0] != 1.f || alpha[1] != 1.f ||
              alpha[2] != 1.f || alpha[3] != 1.f)) {
#pragma unroll
      for (int t = 0; t < 24; ++t) {
#pragma unroll
        for (int r = 0; r < 4; ++r) acc[t][r] *= alpha[r];
      }
    }
    __syncthreads();

#pragma unroll
    for (int r = 0; r < 4; ++r) {
      int row = quad * 4 + r;
      l_run[r] = l_run[r] * alpha[r] +
                 (ssum[row] + ssum[16 + row] + ssum[32 + row] + ssum[48 + row]);
    }

    // PV: A = P (from LDS), B = VT rows direct from global (L2/L3-resident)
    // FULL unroll: constant acc indices (partial unroll => scratch demotion)
    f16x8 pf0 = *(const f16x8*)&p_lds[l15 * 72 + quad * 8];
    f16x8 pf1 = *(const f16x8*)&p_lds[l15 * 72 + 32 + quad * 8];
    const f16* vp = vb + m0 + quad * 8;
#pragma unroll
    for (int ct = 0; ct < 24; ++ct) {
      f16x8 v0 = *(const f16x8*)(vp + (size_t)ct * (16 * 4096));
      f16x8 v1 = *(const f16x8*)(vp + (size_t)ct * (16 * 4096) + 32);
      acc[ct] = __builtin_amdgcn_mfma_f32_16x16x32_f16(pf0, v0, acc[ct], 0, 0, 0);
      acc[ct] = __builtin_amdgcn_mfma_f32_16x16x32_f16(pf1, v1, acc[ct], 0, 0, 0);
    }
  }

  // ---------------- epilogue ----------------
  __syncthreads();  // all p_lds/g_lds reads done before aliasing as meanL/e2L
  float inv[4];
#pragma unroll
  for (int r = 0; r < 4; ++r) inv[r] = 1.0f / l_run[r];

  float* meanL = (float*)smem;           // [512][18]
  float* e2L = (float*)(smem + 36864);   // [512][18]

  // phase 1: write mean (grp 0) and e2-hi (grp 1)
#pragma unroll
  for (int ct = 0; ct < 24; ++ct) {
    int vcol = wv * 384 + ct * 16 + l15;
    int grp = vcol >> 9;
    int c = vcol & 511;
    if (grp < 2) {
      float* dst = (grp == 0) ? meanL : e2L;
#pragma unroll
      for (int r = 0; r < 4; ++r) dst[c * 18 + quad * 4 + r] = acc[ct][r] * inv[r];
    }
  }
  __syncthreads();
  // phase 2: add e2-lo (grp 2)
#pragma unroll
  for (int ct = 0; ct < 24; ++ct) {
    int vcol = wv * 384 + ct * 16 + l15;
    int grp = vcol >> 9;
    int c = vcol & 511;
    if (grp == 2) {
#pragma unroll
      for (int r = 0; r < 4; ++r) e2L[c * 18 + quad * 4 + r] += acc[ct][r] * inv[r];
    }
  }
  __syncthreads();

  // final: out[b][c][n0+nl] = std * c_x + mean
#pragma unroll 4
  for (int rep = 0; rep < 32; ++rep) {
    int idx = tid + rep * 256;
    int c = idx >> 4;
    int nl = idx & 15;
    float m = meanL[c * 18 + nl];
    float e2v = e2L[c * 18 + nl];
    float sd = sqrtf(fmaxf(e2v - m * m, 0.f));
    size_t gi = ((size_t)b * 512 + c) * 4096 + n0 + nl;
    out[gi] = sd * cx[gi] + m;
  }
}

// ---------------------------------------------------------------------------
extern "C" void kernel_launch(void* const* d_in, const int* in_sizes, int n_in,
                              void* d_out, int out_size, void* d_ws, size_t ws_size,
                              hipStream_t stream) {
  (void)in_sizes; (void)n_in; (void)out_size;
  const float* c_x  = (const float*)d_in[0];
  const float* s_x  = (const float*)d_in[1];
  const float* c_1x = (const float*)d_in[2];
  const float* s_1x = (const float*)d_in[3];
  const float* f_w  = (const float*)d_in[4];
  const float* f_b  = (const float*)d_in[5];
  const float* g_w  = (const float*)d_in[6];
  const float* g_b  = (const float*)d_in[7];
  const float* h_w  = (const float*)d_in[8];
  const float* h_b  = (const float*)d_in[9];
  float* out = (float*)d_out;

  const size_t fe = (size_t)4 * 4096 * 512;  // elements per F/G buffer
  f16* Fb = (f16*)d_ws;
  f16* Gb = Fb + fe;
  f16* VT = Gb + fe;
  const size_t need = fe * 2 * sizeof(f16) * 2 + (size_t)4 * 1536 * 4096 * sizeof(f16);
  if (ws_size < need) return;  // 80 MiB required; fail loudly (output stays poisoned)

  dim3 blk(256);
  dim3 gP(64, 8, 4);
  conv_ik<<<gP, blk, 0, stream>>>(c_1x, f_w, f_b, Fb);
  conv_ik<<<gP, blk, 0, stream>>>(s_1x, g_w, g_b, Gb);
  conv_vt<<<gP, blk, 0, stream>>>(s_x, h_w, h_b, VT);
  adaattn_flash<<<dim3(256, 4), blk, 0, stream>>>(Fb, Gb, VT, c_x, out);
}